// Round 14
// baseline (279.602 us; speedup 1.0000x reference)
//
#include <hip/hip_runtime.h>
#include <hip/hip_bf16.h>
#include <math.h>

#define B_ 2
#define S_ 2048
#define E_ 768
#define H_ 12
#define D_ 64
#define M_ (B_*S_)   // 4096 rows total

typedef unsigned short ush;
using short8 = __attribute__((ext_vector_type(8))) short;   // 8 bf16 (4 VGPRs)
using f32x4  = __attribute__((ext_vector_type(4))) float;   // MFMA C/D

__device__ __forceinline__ ush f2b(float x) {               // fp32 -> bf16 RNE
    union { float f; unsigned u; } v; v.f = x;
    unsigned r = v.u + 0x7fffu + ((v.u >> 16) & 1u);
    return (ush)(r >> 16);
}
// fp32 pair -> packed bf16: round-half-up + v_perm_b32 (3 VALU ops).
__device__ __forceinline__ unsigned pack2(float x, float y) {
    unsigned bx = __float_as_uint(x) + 0x8000u;
    unsigned by = __float_as_uint(y) + 0x8000u;
    return __builtin_amdgcn_perm(by, bx, 0x07060302u);  // [bx.hi16 | by.hi16<<16]
}

// ---------------------------------------------------------------------------
// Kernel 1: QKV projection, single-bf16 MFMA GEMM, double-buffered staging
// (unchanged from R13 — verified). grid (M/64, E/64=H, 3).
// ---------------------------------------------------------------------------
__global__ __launch_bounds__(256) void qkv_mfma_kernel(
    const float* __restrict__ q_in, const float* __restrict__ k_in, const float* __restrict__ v_in,
    const float* __restrict__ wq, const float* __restrict__ bq,
    const float* __restrict__ wk, const float* __restrict__ bk,
    const float* __restrict__ wv, const float* __restrict__ bv,
    ush* __restrict__ Qb, ush* __restrict__ Kb, ush* __restrict__ Vtb)
{
    const int z = blockIdx.z;
    const float* __restrict__ X    = (z == 0) ? q_in : (z == 1) ? k_in : v_in;
    const float* __restrict__ W    = (z == 0) ? wq   : (z == 1) ? wk   : wv;
    const float* __restrict__ bias = (z == 0) ? bq   : (z == 1) ? bk   : bv;

    __shared__ ush Ab[2][64 * 72];   // ping-pong [m][k], pitch 72 shorts
    __shared__ ush Bb[2][64 * 72];   // ping-pong [n][k]

    const int m0 = blockIdx.x * 64;
    const int n0 = blockIdx.y * 64;
    const int t  = threadIdx.x;
    const int wid  = t >> 6;
    const int lane = t & 63;
    const int quad = lane >> 4;
    const int l16  = lane & 15;
    const int wr = (wid >> 1) * 32;    // wave row offset in tile
    const int wc = (wid & 1) * 32;     // wave col offset in tile
    const int rr = t >> 4;             // staging row base
    const int c4 = t & 15;             // staging float4 chunk

    f32x4 acc[2][2];
    #pragma unroll
    for (int i = 0; i < 2; ++i)
        #pragma unroll
        for (int j = 0; j < 2; ++j) acc[i][j] = (f32x4){0.f, 0.f, 0.f, 0.f};

    float4 ax[4], wx[4];
    #pragma unroll
    for (int i = 0; i < 4; ++i) {
        ax[i] = *(const float4*)&X[(size_t)(m0 + rr + i * 16) * E_ + c4 * 4];
        wx[i] = *(const float4*)&W[(size_t)(n0 + rr + i * 16) * E_ + c4 * 4];
    }
    #pragma unroll
    for (int i = 0; i < 4; ++i) {
        uint2 pa; pa.x = pack2(ax[i].x, ax[i].y); pa.y = pack2(ax[i].z, ax[i].w);
        *(uint2*)&Ab[0][(rr + i * 16) * 72 + c4 * 4] = pa;
        uint2 pw; pw.x = pack2(wx[i].x, wx[i].y); pw.y = pack2(wx[i].z, wx[i].w);
        *(uint2*)&Bb[0][(rr + i * 16) * 72 + c4 * 4] = pw;
    }

    int p = 0;
    for (int kt = 0; kt < E_ / 64; ++kt) {
        __syncthreads();   // buf[p] writes visible; buf[p^1] readers (kt-1) done
        const bool more = (kt + 1) < E_ / 64;
        if (more) {
            const int kn = (kt + 1) * 64;
            #pragma unroll
            for (int i = 0; i < 4; ++i) {
                ax[i] = *(const float4*)&X[(size_t)(m0 + rr + i * 16) * E_ + kn + c4 * 4];
                wx[i] = *(const float4*)&W[(size_t)(n0 + rr + i * 16) * E_ + kn + c4 * 4];
            }
        }

        #pragma unroll
        for (int ks = 0; ks < 2; ++ks) {      // two 32-wide K sub-steps
            short8 b0 = *(const short8*)&Bb[p][(wc + l16) * 72 + quad * 8 + ks * 32];
            short8 b1 = *(const short8*)&Bb[p][(wc + 16 + l16) * 72 + quad * 8 + ks * 32];
            #pragma unroll
            for (int mi = 0; mi < 2; ++mi) {
                short8 a = *(const short8*)&Ab[p][(wr + mi * 16 + l16) * 72 + quad * 8 + ks * 32];
                acc[mi][0] = __builtin_amdgcn_mfma_f32_16x16x32_bf16(a, b0, acc[mi][0], 0, 0, 0);
                acc[mi][1] = __builtin_amdgcn_mfma_f32_16x16x32_bf16(a, b1, acc[mi][1], 0, 0, 0);
            }
        }

        if (more) {
            #pragma unroll
            for (int i = 0; i < 4; ++i) {
                uint2 pa; pa.x = pack2(ax[i].x, ax[i].y); pa.y = pack2(ax[i].z, ax[i].w);
                *(uint2*)&Ab[p ^ 1][(rr + i * 16) * 72 + c4 * 4] = pa;
                uint2 pw; pw.x = pack2(wx[i].x, wx[i].y); pw.y = pack2(wx[i].z, wx[i].w);
                *(uint2*)&Bb[p ^ 1][(rr + i * 16) * 72 + c4 * 4] = pw;
            }
        }
        p ^= 1;
    }

    // ---- epilogue ----  (whole block is one head: h = blockIdx.y)
    const int h = blockIdx.y;
    const float ln1e4 = 9.210340371976184f;  // ln(10000)
    if (z < 2) {
        ush* __restrict__ Ob = (z == 0) ? Qb : Kb;
        #pragma unroll
        for (int ni = 0; ni < 2; ++ni) {
            const int d = wc + ni * 16 + l16;        // 0..63 within head
            const float bw = bias[n0 + d];
            const float inv_freq = expf(-((float)(d & 62) / 64.f) * ln1e4);
            const bool even = (d & 1) == 0;
            #pragma unroll
            for (int mi = 0; mi < 2; ++mi) {
                #pragma unroll
                for (int r = 0; r < 4; ++r) {
                    const int m = m0 + wr + mi * 16 + quad * 4 + r;
                    const int bb = m >> 11, s = m & (S_ - 1);
                    float v = acc[mi][ni][r] + bw;
                    float part = __shfl_xor(v, 1);          // pair value (d^1)
                    float sn, cs;
                    sincosf((float)s * inv_freq, &sn, &cs);
                    float rot = even ? (v * cs - part * sn) : (v * cs + part * sn);
                    ush pr = f2b(rot);
                    ush pp = (ush)__shfl_xor((int)pr, 1);   // partner's rotated
                    if (even) {
                        size_t o = (((size_t)bb * H_ + h) * S_ + s) * (size_t)D_ + d;
                        *(unsigned*)&Ob[o] = (unsigned)pr | ((unsigned)pp << 16);
                    }
                }
            }
        }
    } else {
        #pragma unroll
        for (int ni = 0; ni < 2; ++ni) {
            const int d = wc + ni * 16 + l16;
            const float bw = bias[n0 + d];
            #pragma unroll
            for (int mi = 0; mi < 2; ++mi) {
                const int m = m0 + wr + mi * 16 + quad * 4;  // r spans 4 consecutive s
                const int bb = m >> 11, sb = m & (S_ - 1);
                size_t o = (((size_t)bb * H_ + h) * D_ + d) * (size_t)S_ + sb;
                uint2 pk;
                pk.x = pack2(acc[mi][ni][0] + bw, acc[mi][ni][1] + bw);
                pk.y = pack2(acc[mi][ni][2] + bw, acc[mi][ni][3] + bw);
                *(uint2*)&Vtb[o] = pk;
            }
        }
    }
}

// ---------------------------------------------------------------------------
// Kernel 2: MFMA flash attention, FIXED-MAX softmax, DOUBLE-BUFFERED K/V.
// R13 counters (MfmaUtil 16%, VALUBusy 29%, HBM 11%, occupancy grid-capped
// at 3 blocks/CU) say the K-loop was staging-latency-bound like R12's GEMM.
// Ping-pong Ks/Vt + register prefetch hides global latency under QK^T+softmax.
// Ps barrier KEPT: Ps is cross-lane-through-LDS (m120 pattern needs it).
// grid (S/64, H, B), block 256. LDS 51 KB -> 3 blocks/CU (= grid cap).
// ---------------------------------------------------------------------------
__global__ __launch_bounds__(256) void attn_kernel(
    const ush* __restrict__ Qb, const ush* __restrict__ Kb, const ush* __restrict__ Vtb,
    const float* __restrict__ pb, const int* __restrict__ mask, const float* __restrict__ coeff,
    float* __restrict__ Att)
{
    __shared__ ush  Ks[2][64 * 72];    // ping-pong [key][d]
    __shared__ ush  Vt[2][80 * 72];    // ping-pong [d][key]; rows 64..79 = ones block
    __shared__ ush  Ps[64 * 72];       // P rows [q][key] (wave-strip private)
    __shared__ float kb_s[2][64];      // per-key bias: (mask?0:-1e30) - ch*pb[k]

    const int q0 = blockIdx.x * 64;
    const int h  = blockIdx.y;
    const int b  = blockIdx.z;
    const int t  = threadIdx.x;
    const int wid = t >> 6;
    const int lane = t & 63;
    const int quad = lane >> 4;
    const int l16  = lane & 15;

    const int bh = b * H_ + h;
    const float ch = coeff[h];
    const ush* __restrict__ Kbase = Kb + (size_t)bh * S_ * D_;
    const ush* __restrict__ Vbase = Vtb + (size_t)bh * D_ * S_;

    // ones-column rows in BOTH buffers (staging only touches rows 0..63)
    {
        int r2 = 64 + (t >> 4);        // 64..79
        int k2 = (t & 15) * 4;         // 0..60
        ush v = (r2 == 64) ? (ush)0x3F80 : (ush)0;   // bf16 1.0 / 0.0
        #pragma unroll
        for (int pp = 0; pp < 2; ++pp) {
            Vt[pp][r2 * 72 + k2 + 0] = v;
            Vt[pp][r2 * 72 + k2 + 1] = v;
            Vt[pp][r2 * 72 + k2 + 2] = v;
            Vt[pp][r2 * 72 + k2 + 3] = v;
        }
    }

    const int qrow = q0 + wid * 16 + l16;
    short8 aQ[2];
    #pragma unroll
    for (int ks = 0; ks < 2; ++ks)
        aQ[ks] = *(const short8*)&Qb[((size_t)bh * S_ + qrow) * D_ + quad * 8 + ks * 32];

    float hp[4];
    #pragma unroll
    for (int r = 0; r < 4; ++r)
        hp[r] = ch * pb[b * S_ + q0 + wid * 16 + quad * 4 + r];

    f32x4 O[5];                        // O[4] = row-sum accumulator (ones-column)
    #pragma unroll
    for (int g = 0; g < 5; ++g) O[g] = (f32x4){0.f, 0.f, 0.f, 0.f};

    // ---- prefetch tile 0 into regs, write buf 0 ----
    uint4 kreg[2], vreg[2];
    float kbv = 0.f;
    #pragma unroll
    for (int it = 0; it < 2; ++it) {
        int idx = t + it * 256, row = idx >> 3, chk = idx & 7;
        kreg[it] = ((const uint4*)Kbase)[idx];
        vreg[it] = ((const uint4*)(Vbase + (size_t)row * S_))[chk];
    }
    if (t < 64) {
        int gi = b * S_ + t;
        kbv = (mask[gi] ? 0.f : -1e30f) - ch * pb[gi];
    }
    #pragma unroll
    for (int it = 0; it < 2; ++it) {
        int idx = t + it * 256, row = idx >> 3, chk = idx & 7;
        *(uint4*)&Ks[0][row * 72 + chk * 8] = kreg[it];
        *(uint4*)&Vt[0][row * 72 + chk * 8] = vreg[it];
    }
    if (t < 64) kb_s[0][t] = kbv;

    int p = 0;
    for (int kt = 0; kt < S_ / 64; ++kt) {
        __syncthreads();               // buf[p] visible; buf[p^1] readers (kt-1) done
        const bool more = (kt + 1) < S_ / 64;
        if (more) {
            const int kn = (kt + 1) * 64;
            #pragma unroll
            for (int it = 0; it < 2; ++it) {
                int idx = t + it * 256, row = idx >> 3, chk = idx & 7;
                kreg[it] = ((const uint4*)(Kbase + (size_t)kn * D_))[idx];
                vreg[it] = ((const uint4*)(Vbase + (size_t)row * S_ + kn))[chk];
            }
            if (t < 64) {
                int gi = b * S_ + kn + t;
                kbv = (mask[gi] ? 0.f : -1e30f) - ch * pb[gi];
            }
        }

        // ---- QK^T from buf p ----
        f32x4 Sc[4];
        #pragma unroll
        for (int cg = 0; cg < 4; ++cg) Sc[cg] = (f32x4){0.f, 0.f, 0.f, 0.f};
        #pragma unroll
        for (int ks = 0; ks < 2; ++ks) {
            #pragma unroll
            for (int cg = 0; cg < 4; ++cg) {
                short8 bK = *(const short8*)&Ks[p][(cg * 16 + l16) * 72 + quad * 8 + ks * 32];
                Sc[cg] = __builtin_amdgcn_mfma_f32_16x16x32_bf16(aQ[ks], bK, Sc[cg], 0, 0, 0);
            }
        }

        // ---- fixed-max softmax numerators -> Ps (bf16 truncation) ----
        float kbl[4];
        #pragma unroll
        for (int cg = 0; cg < 4; ++cg) kbl[cg] = kb_s[p][cg * 16 + l16];
        #pragma unroll
        for (int cg = 0; cg < 4; ++cg)
            #pragma unroll
            for (int r = 0; r < 4; ++r) {
                float s = fmaf(Sc[cg][r], 0.125f, hp[r] + kbl[cg]);
                float pr = __expf(s);  // masked: s ~ -1e30 -> p = 0 exactly
                Ps[(wid * 16 + quad * 4 + r) * 72 + cg * 16 + l16] =
                    (ush)(__float_as_uint(pr) >> 16);
            }
        __syncthreads();               // Ps cross-lane visibility (within strip)

        // ---- PV (+ ones-column row-sum into O[4]) from buf p ----
        #pragma unroll
        for (int ks = 0; ks < 2; ++ks) {
            short8 aP = *(const short8*)&Ps[(wid * 16 + l16) * 72 + quad * 8 + ks * 32];
            #pragma unroll
            for (int g = 0; g < 5; ++g) {
                short8 bV = *(const short8*)&Vt[p][(g * 16 + l16) * 72 + quad * 8 + ks * 32];
                O[g] = __builtin_amdgcn_mfma_f32_16x16x32_bf16(aP, bV, O[g], 0, 0, 0);
            }
        }

        // ---- write prefetched tile into buf p^1 ----
        if (more) {
            #pragma unroll
            for (int it = 0; it < 2; ++it) {
                int idx = t + it * 256, row = idx >> 3, chk = idx & 7;
                *(uint4*)&Ks[p ^ 1][row * 72 + chk * 8] = kreg[it];
                *(uint4*)&Vt[p ^ 1][row * 72 + chk * 8] = vreg[it];
            }
            if (t < 64) kb_s[p ^ 1][t] = kbv;
        }
        p ^= 1;
    }

    // epilogue: l lives in lane l16==0 of each quad (col 64 of ones block)
    #pragma unroll
    for (int r = 0; r < 4; ++r) {
        const float l  = __shfl(O[4][r], (lane & 48));   // lane quad*16 (l16=0)
        const float rl = 1.f / l;
        const size_t ob = ((size_t)b * S_ + q0 + wid * 16 + quad * 4 + r) * E_ + h * 64;
        #pragma unroll
        for (int g = 0; g < 4; ++g)
            Att[ob + g * 16 + l16] = O[g][r] * rl;
    }
}

// ---------------------------------------------------------------------------
// Kernel 3: output projection, single-bf16 MFMA GEMM, double-buffered staging
// (unchanged from R13). grid (M/64, E/64).
// ---------------------------------------------------------------------------
__global__ __launch_bounds__(256) void fc_mfma_kernel(
    const float* __restrict__ Xin, const float* __restrict__ W,
    const float* __restrict__ bias, float* __restrict__ Out)
{
    __shared__ ush Ab[2][64 * 72];
    __shared__ ush Bb[2][64 * 72];

    const int m0 = blockIdx.x * 64;
    const int n0 = blockIdx.y * 64;
    const int t  = threadIdx.x;
    const int wid  = t >> 6;
    const int lane = t & 63;
    const int quad = lane >> 4;
    const int l16  = lane & 15;
    const int wr = (wid >> 1) * 32;
    const int wc = (wid & 1) * 32;
    const int rr = t >> 4;
    const int c4 = t & 15;

    f32x4 acc[2][2];
    #pragma unroll
    for (int i = 0; i < 2; ++i)
        #pragma unroll
        for (int j = 0; j < 2; ++j) acc[i][j] = (f32x4){0.f, 0.f, 0.f, 0.f};

    float4 ax[4], wx[4];
    #pragma unroll
    for (int i = 0; i < 4; ++i) {
        ax[i] = *(const float4*)&Xin[(size_t)(m0 + rr + i * 16) * E_ + c4 * 4];
        wx[i] = *(const float4*)&W[(size_t)(n0 + rr + i * 16) * E_ + c4 * 4];
    }
    #pragma unroll
    for (int i = 0; i < 4; ++i) {
        uint2 pa; pa.x = pack2(ax[i].x, ax[i].y); pa.y = pack2(ax[i].z, ax[i].w);
        *(uint2*)&Ab[0][(rr + i * 16) * 72 + c4 * 4] = pa;
        uint2 pw; pw.x = pack2(wx[i].x, wx[i].y); pw.y = pack2(wx[i].z, wx[i].w);
        *(uint2*)&Bb[0][(rr + i * 16) * 72 + c4 * 4] = pw;
    }

    int p = 0;
    for (int kt = 0; kt < E_ / 64; ++kt) {
        __syncthreads();
        const bool more = (kt + 1) < E_ / 64;
        if (more) {
            const int kn = (kt + 1) * 64;
            #pragma unroll
            for (int i = 0; i < 4; ++i) {
                ax[i] = *(const float4*)&Xin[(size_t)(m0 + rr + i * 16) * E_ + kn + c4 * 4];
                wx[i] = *(const float4*)&W[(size_t)(n0 + rr + i * 16) * E_ + kn + c4 * 4];
            }
        }

        #pragma unroll
        for (int ks = 0; ks < 2; ++ks) {
            short8 b0 = *(const short8*)&Bb[p][(wc + l16) * 72 + quad * 8 + ks * 32];
            short8 b1 = *(const short8*)&Bb[p][(wc + 16 + l16) * 72 + quad * 8 + ks * 32];
            #pragma unroll
            for (int mi = 0; mi < 2; ++mi) {
                short8 a = *(const short8*)&Ab[p][(wr + mi * 16 + l16) * 72 + quad * 8 + ks * 32];
                acc[mi][0] = __builtin_amdgcn_mfma_f32_16x16x32_bf16(a, b0, acc[mi][0], 0, 0, 0);
                acc[mi][1] = __builtin_amdgcn_mfma_f32_16x16x32_bf16(a, b1, acc[mi][1], 0, 0, 0);
            }
        }

        if (more) {
            #pragma unroll
            for (int i = 0; i < 4; ++i) {
                uint2 pa; pa.x = pack2(ax[i].x, ax[i].y); pa.y = pack2(ax[i].z, ax[i].w);
                *(uint2*)&Ab[p ^ 1][(rr + i * 16) * 72 + c4 * 4] = pa;
                uint2 pw; pw.x = pack2(wx[i].x, wx[i].y); pw.y = pack2(wx[i].z, wx[i].w);
                *(uint2*)&Bb[p ^ 1][(rr + i * 16) * 72 + c4 * 4] = pw;
            }
        }
        p ^= 1;
    }

    #pragma unroll
    for (int ni = 0; ni < 2; ++ni) {
        const int n = n0 + wc + ni * 16 + l16;
        const float bw = bias[n];
        #pragma unroll
        for (int mi = 0; mi < 2; ++mi)
            #pragma unroll
            for (int r = 0; r < 4; ++r) {
                const int m = m0 + wr + mi * 16 + quad * 4 + r;
                Out[(size_t)m * E_ + n] = acc[mi][ni][r] + bw;
            }
    }
}

// ---------------------------------------------------------------------------
extern "C" void kernel_launch(void* const* d_in, const int* in_sizes, int n_in,
                              void* d_out, int out_size, void* d_ws, size_t ws_size,
                              hipStream_t stream)
{
    const float* q_in  = (const float*)d_in[0];
    const float* k_in  = (const float*)d_in[1];
    const float* v_in  = (const float*)d_in[2];
    const float* pb    = (const float*)d_in[3];
    const int*   mask  = (const int*)d_in[4];
    const float* wq    = (const float*)d_in[5];
    const float* bq    = (const float*)d_in[6];
    const float* wk    = (const float*)d_in[7];
    const float* bk    = (const float*)d_in[8];
    const float* wv    = (const float*)d_in[9];
    const float* bv    = (const float*)d_in[10];
    const float* fw    = (const float*)d_in[11];
    const float* fb    = (const float*)d_in[12];
    const float* coeff = (const float*)d_in[13];
    float* out = (float*)d_out;

    const size_t per = (size_t)B_ * H_ * S_ * D_;   // 3,145,728 elements
    float* Att = (float*)d_ws;                       // [B,S,E] fp32
    ush*   Qb  = (ush*)(Att + per);                  // bf16 [B,H,S,D]
    ush*   Kb  = Qb + per;
    ush*   Vtb = Kb + per;                           // bf16 [B,H,D,S]

    qkv_mfma_kernel<<<dim3(M_ / 64, E_ / 64, 3), 256, 0, stream>>>(
        q_in, k_in, v_in, wq, bq, wk, bk, wv, bv, Qb, Kb, Vtb);

    attn_kernel<<<dim3(S_ / 64, H_, B_), 256, 0, stream>>>(
        Qb, Kb, Vtb, pb, mask, coeff, Att);

    fc_mfma_kernel<<<dim3(M_ / 64, E_ / 64), 256, 0, stream>>>(Att, fw, fb, out);
}

// Round 15
// 227.791 us; speedup vs baseline: 1.2274x; 1.2274x over previous
//
#include <hip/hip_runtime.h>
#include <hip/hip_bf16.h>
#include <math.h>

#define B_ 2
#define S_ 2048
#define E_ 768
#define H_ 12
#define D_ 64
#define M_ (B_*S_)   // 4096 rows total

typedef unsigned short ush;
using short8 = __attribute__((ext_vector_type(8))) short;   // 8 bf16 (4 VGPRs)
using f32x4  = __attribute__((ext_vector_type(4))) float;   // MFMA C/D

__device__ __forceinline__ ush f2b(float x) {               // fp32 -> bf16 RNE
    union { float f; unsigned u; } v; v.f = x;
    unsigned r = v.u + 0x7fffu + ((v.u >> 16) & 1u);
    return (ush)(r >> 16);
}
// fp32 pair -> packed bf16: round-half-up + v_perm_b32 (3 VALU ops).
__device__ __forceinline__ unsigned pack2(float x, float y) {
    unsigned bx = __float_as_uint(x) + 0x8000u;
    unsigned by = __float_as_uint(y) + 0x8000u;
    return __builtin_amdgcn_perm(by, bx, 0x07060302u);  // [bx.hi16 | by.hi16<<16]
}

// ---------------------------------------------------------------------------
// Kernel 1: QKV projection, single-bf16 MFMA GEMM, double-buffered staging
// (unchanged from R13 — verified). grid (M/64, E/64=H, 3).
// ---------------------------------------------------------------------------
__global__ __launch_bounds__(256) void qkv_mfma_kernel(
    const float* __restrict__ q_in, const float* __restrict__ k_in, const float* __restrict__ v_in,
    const float* __restrict__ wq, const float* __restrict__ bq,
    const float* __restrict__ wk, const float* __restrict__ bk,
    const float* __restrict__ wv, const float* __restrict__ bv,
    ush* __restrict__ Qb, ush* __restrict__ Kb, ush* __restrict__ Vtb)
{
    const int z = blockIdx.z;
    const float* __restrict__ X    = (z == 0) ? q_in : (z == 1) ? k_in : v_in;
    const float* __restrict__ W    = (z == 0) ? wq   : (z == 1) ? wk   : wv;
    const float* __restrict__ bias = (z == 0) ? bq   : (z == 1) ? bk   : bv;

    __shared__ ush Ab[2][64 * 72];   // ping-pong [m][k], pitch 72 shorts
    __shared__ ush Bb[2][64 * 72];   // ping-pong [n][k]

    const int m0 = blockIdx.x * 64;
    const int n0 = blockIdx.y * 64;
    const int t  = threadIdx.x;
    const int wid  = t >> 6;
    const int lane = t & 63;
    const int quad = lane >> 4;
    const int l16  = lane & 15;
    const int wr = (wid >> 1) * 32;    // wave row offset in tile
    const int wc = (wid & 1) * 32;     // wave col offset in tile
    const int rr = t >> 4;             // staging row base
    const int c4 = t & 15;             // staging float4 chunk

    f32x4 acc[2][2];
    #pragma unroll
    for (int i = 0; i < 2; ++i)
        #pragma unroll
        for (int j = 0; j < 2; ++j) acc[i][j] = (f32x4){0.f, 0.f, 0.f, 0.f};

    float4 ax[4], wx[4];
    #pragma unroll
    for (int i = 0; i < 4; ++i) {
        ax[i] = *(const float4*)&X[(size_t)(m0 + rr + i * 16) * E_ + c4 * 4];
        wx[i] = *(const float4*)&W[(size_t)(n0 + rr + i * 16) * E_ + c4 * 4];
    }
    #pragma unroll
    for (int i = 0; i < 4; ++i) {
        uint2 pa; pa.x = pack2(ax[i].x, ax[i].y); pa.y = pack2(ax[i].z, ax[i].w);
        *(uint2*)&Ab[0][(rr + i * 16) * 72 + c4 * 4] = pa;
        uint2 pw; pw.x = pack2(wx[i].x, wx[i].y); pw.y = pack2(wx[i].z, wx[i].w);
        *(uint2*)&Bb[0][(rr + i * 16) * 72 + c4 * 4] = pw;
    }

    int p = 0;
    for (int kt = 0; kt < E_ / 64; ++kt) {
        __syncthreads();   // buf[p] writes visible; buf[p^1] readers (kt-1) done
        const bool more = (kt + 1) < E_ / 64;
        if (more) {
            const int kn = (kt + 1) * 64;
            #pragma unroll
            for (int i = 0; i < 4; ++i) {
                ax[i] = *(const float4*)&X[(size_t)(m0 + rr + i * 16) * E_ + kn + c4 * 4];
                wx[i] = *(const float4*)&W[(size_t)(n0 + rr + i * 16) * E_ + kn + c4 * 4];
            }
        }

        #pragma unroll
        for (int ks = 0; ks < 2; ++ks) {      // two 32-wide K sub-steps
            short8 b0 = *(const short8*)&Bb[p][(wc + l16) * 72 + quad * 8 + ks * 32];
            short8 b1 = *(const short8*)&Bb[p][(wc + 16 + l16) * 72 + quad * 8 + ks * 32];
            #pragma unroll
            for (int mi = 0; mi < 2; ++mi) {
                short8 a = *(const short8*)&Ab[p][(wr + mi * 16 + l16) * 72 + quad * 8 + ks * 32];
                acc[mi][0] = __builtin_amdgcn_mfma_f32_16x16x32_bf16(a, b0, acc[mi][0], 0, 0, 0);
                acc[mi][1] = __builtin_amdgcn_mfma_f32_16x16x32_bf16(a, b1, acc[mi][1], 0, 0, 0);
            }
        }

        if (more) {
            #pragma unroll
            for (int i = 0; i < 4; ++i) {
                uint2 pa; pa.x = pack2(ax[i].x, ax[i].y); pa.y = pack2(ax[i].z, ax[i].w);
                *(uint2*)&Ab[p ^ 1][(rr + i * 16) * 72 + c4 * 4] = pa;
                uint2 pw; pw.x = pack2(wx[i].x, wx[i].y); pw.y = pack2(wx[i].z, wx[i].w);
                *(uint2*)&Bb[p ^ 1][(rr + i * 16) * 72 + c4 * 4] = pw;
            }
        }
        p ^= 1;
    }

    // ---- epilogue ----  (whole block is one head: h = blockIdx.y)
    const int h = blockIdx.y;
    const float ln1e4 = 9.210340371976184f;  // ln(10000)
    if (z < 2) {
        ush* __restrict__ Ob = (z == 0) ? Qb : Kb;
        #pragma unroll
        for (int ni = 0; ni < 2; ++ni) {
            const int d = wc + ni * 16 + l16;        // 0..63 within head
            const float bw = bias[n0 + d];
            const float inv_freq = expf(-((float)(d & 62) / 64.f) * ln1e4);
            const bool even = (d & 1) == 0;
            #pragma unroll
            for (int mi = 0; mi < 2; ++mi) {
                #pragma unroll
                for (int r = 0; r < 4; ++r) {
                    const int m = m0 + wr + mi * 16 + quad * 4 + r;
                    const int bb = m >> 11, s = m & (S_ - 1);
                    float v = acc[mi][ni][r] + bw;
                    float part = __shfl_xor(v, 1);          // pair value (d^1)
                    float sn, cs;
                    sincosf((float)s * inv_freq, &sn, &cs);
                    float rot = even ? (v * cs - part * sn) : (v * cs + part * sn);
                    ush pr = f2b(rot);
                    ush pp = (ush)__shfl_xor((int)pr, 1);   // partner's rotated
                    if (even) {
                        size_t o = (((size_t)bb * H_ + h) * S_ + s) * (size_t)D_ + d;
                        *(unsigned*)&Ob[o] = (unsigned)pr | ((unsigned)pp << 16);
                    }
                }
            }
        }
    } else {
        #pragma unroll
        for (int ni = 0; ni < 2; ++ni) {
            const int d = wc + ni * 16 + l16;
            const float bw = bias[n0 + d];
            #pragma unroll
            for (int mi = 0; mi < 2; ++mi) {
                const int m = m0 + wr + mi * 16 + quad * 4;  // r spans 4 consecutive s
                const int bb = m >> 11, sb = m & (S_ - 1);
                size_t o = (((size_t)bb * H_ + h) * D_ + d) * (size_t)S_ + sb;
                uint2 pk;
                pk.x = pack2(acc[mi][ni][0] + bw, acc[mi][ni][1] + bw);
                pk.y = pack2(acc[mi][ni][2] + bw, acc[mi][ni][3] + bw);
                *(uint2*)&Vtb[o] = pk;
            }
        }
    }
}

// ---------------------------------------------------------------------------
// Kernel 2: MFMA flash attention, FIXED-MAX softmax — R13 structure REVERTED
// (R14's K/V register dbuf spilled: WRITE_SIZE 12->132 MB, attn 72->127 µs).
// One change vs R13: mid-iteration __syncthreads removed. Ps strips are
// wave-private (rows wid*16..+15 written & read only by wave wid); the
// cross-LANE dependency is intra-wave through the same LDS buffer, ordered
// by program order + compiler lgkmcnt waits — no block barrier needed.
// grid (S/64, H, B), block 256.
// ---------------------------------------------------------------------------
__global__ __launch_bounds__(256) void attn_kernel(
    const ush* __restrict__ Qb, const ush* __restrict__ Kb, const ush* __restrict__ Vtb,
    const float* __restrict__ pb, const int* __restrict__ mask, const float* __restrict__ coeff,
    float* __restrict__ Att)
{
    __shared__ ush  Ks[64 * 72];       // [key][d]
    __shared__ ush  Vt[80 * 72];       // [d][key]; rows 64..79 = ones-column block
    __shared__ ush  Ps[64 * 72];       // P rows [q][key] (wave-strip private)
    __shared__ float kb_s[64];         // per-key bias: (mask?0:-1e30) - ch*pb[k]

    const int q0 = blockIdx.x * 64;
    const int h  = blockIdx.y;
    const int b  = blockIdx.z;
    const int t  = threadIdx.x;
    const int wid = t >> 6;
    const int lane = t & 63;
    const int quad = lane >> 4;
    const int l16  = lane & 15;

    const int bh = b * H_ + h;
    const float ch = coeff[h];

    // ones-column rows (written once; staging only touches rows 0..63)
    {
        int r2 = 64 + (t >> 4);        // 64..79
        int k2 = (t & 15) * 4;         // 0..60
        ush v = (r2 == 64) ? (ush)0x3F80 : (ush)0;   // bf16 1.0 / 0.0
        Vt[r2 * 72 + k2 + 0] = v;
        Vt[r2 * 72 + k2 + 1] = v;
        Vt[r2 * 72 + k2 + 2] = v;
        Vt[r2 * 72 + k2 + 3] = v;
    }

    const int qrow = q0 + wid * 16 + l16;
    short8 aQ[2];
    #pragma unroll
    for (int ks = 0; ks < 2; ++ks)
        aQ[ks] = *(const short8*)&Qb[((size_t)bh * S_ + qrow) * D_ + quad * 8 + ks * 32];

    float hp[4];
    #pragma unroll
    for (int r = 0; r < 4; ++r)
        hp[r] = ch * pb[b * S_ + q0 + wid * 16 + quad * 4 + r];

    f32x4 O[5];                        // O[4] = row-sum accumulator (ones-column)
    #pragma unroll
    for (int g = 0; g < 5; ++g) O[g] = (f32x4){0.f, 0.f, 0.f, 0.f};

    for (int kt = 0; kt < S_ / 64; ++kt) {
        const int k0 = kt * 64;
        __syncthreads();               // prior tile's frag reads done (also orders init)
        {
            const uint4* srcK = (const uint4*)(Kb + ((size_t)bh * S_ + k0) * D_);
            #pragma unroll
            for (int it = 0; it < 2; ++it) {
                int idx = t + it * 256;
                int row = idx >> 3, chk = idx & 7;
                *(uint4*)&Ks[row * 72 + chk * 8] = srcK[idx];
                const uint4* srcV = (const uint4*)(Vtb + ((size_t)bh * D_ + row) * S_ + k0);
                *(uint4*)&Vt[row * 72 + chk * 8] = srcV[chk];
            }
        }
        if (t < 64) {
            int gi = b * S_ + k0 + t;
            kb_s[t] = (mask[gi] ? 0.f : -1e30f) - ch * pb[gi];
        }
        __syncthreads();

        // ---- QK^T ----
        f32x4 Sc[4];
        #pragma unroll
        for (int cg = 0; cg < 4; ++cg) Sc[cg] = (f32x4){0.f, 0.f, 0.f, 0.f};
        #pragma unroll
        for (int ks = 0; ks < 2; ++ks) {
            #pragma unroll
            for (int cg = 0; cg < 4; ++cg) {
                short8 bK = *(const short8*)&Ks[(cg * 16 + l16) * 72 + quad * 8 + ks * 32];
                Sc[cg] = __builtin_amdgcn_mfma_f32_16x16x32_bf16(aQ[ks], bK, Sc[cg], 0, 0, 0);
            }
        }

        // ---- fixed-max softmax numerators -> Ps (bf16 truncation) ----
        float kbv[4];
        #pragma unroll
        for (int cg = 0; cg < 4; ++cg) kbv[cg] = kb_s[cg * 16 + l16];
        #pragma unroll
        for (int cg = 0; cg < 4; ++cg)
            #pragma unroll
            for (int r = 0; r < 4; ++r) {
                float s = fmaf(Sc[cg][r], 0.125f, hp[r] + kbv[cg]);
                float p = __expf(s);   // masked: s ~ -1e30 -> p = 0 exactly
                Ps[(wid * 16 + quad * 4 + r) * 72 + cg * 16 + l16] =
                    (ush)(__float_as_uint(p) >> 16);
            }
        // NO __syncthreads here: Ps strip is wave-private; intra-wave LDS
        // RAW is ordered by lgkmcnt (compiler-inserted — aliasing same array).

        // ---- PV (+ ones-column row-sum into O[4]) ----
        #pragma unroll
        for (int ks = 0; ks < 2; ++ks) {
            short8 aP = *(const short8*)&Ps[(wid * 16 + l16) * 72 + quad * 8 + ks * 32];
            #pragma unroll
            for (int g = 0; g < 5; ++g) {
                short8 bV = *(const short8*)&Vt[(g * 16 + l16) * 72 + quad * 8 + ks * 32];
                O[g] = __builtin_amdgcn_mfma_f32_16x16x32_bf16(aP, bV, O[g], 0, 0, 0);
            }
        }
    }

    // epilogue: l lives in lane l16==0 of each quad (col 64 of ones block)
    #pragma unroll
    for (int r = 0; r < 4; ++r) {
        const float l  = __shfl(O[4][r], (lane & 48));   // lane quad*16 (l16=0)
        const float rl = 1.f / l;
        const size_t ob = ((size_t)b * S_ + q0 + wid * 16 + quad * 4 + r) * E_ + h * 64;
        #pragma unroll
        for (int g = 0; g < 4; ++g)
            Att[ob + g * 16 + l16] = O[g][r] * rl;
    }
}

// ---------------------------------------------------------------------------
// Kernel 3: output projection, single-bf16 MFMA GEMM, double-buffered staging
// (unchanged from R13). grid (M/64, E/64).
// ---------------------------------------------------------------------------
__global__ __launch_bounds__(256) void fc_mfma_kernel(
    const float* __restrict__ Xin, const float* __restrict__ W,
    const float* __restrict__ bias, float* __restrict__ Out)
{
    __shared__ ush Ab[2][64 * 72];
    __shared__ ush Bb[2][64 * 72];

    const int m0 = blockIdx.x * 64;
    const int n0 = blockIdx.y * 64;
    const int t  = threadIdx.x;
    const int wid  = t >> 6;
    const int lane = t & 63;
    const int quad = lane >> 4;
    const int l16  = lane & 15;
    const int wr = (wid >> 1) * 32;
    const int wc = (wid & 1) * 32;
    const int rr = t >> 4;
    const int c4 = t & 15;

    f32x4 acc[2][2];
    #pragma unroll
    for (int i = 0; i < 2; ++i)
        #pragma unroll
        for (int j = 0; j < 2; ++j) acc[i][j] = (f32x4){0.f, 0.f, 0.f, 0.f};

    float4 ax[4], wx[4];
    #pragma unroll
    for (int i = 0; i < 4; ++i) {
        ax[i] = *(const float4*)&Xin[(size_t)(m0 + rr + i * 16) * E_ + c4 * 4];
        wx[i] = *(const float4*)&W[(size_t)(n0 + rr + i * 16) * E_ + c4 * 4];
    }
    #pragma unroll
    for (int i = 0; i < 4; ++i) {
        uint2 pa; pa.x = pack2(ax[i].x, ax[i].y); pa.y = pack2(ax[i].z, ax[i].w);
        *(uint2*)&Ab[0][(rr + i * 16) * 72 + c4 * 4] = pa;
        uint2 pw; pw.x = pack2(wx[i].x, wx[i].y); pw.y = pack2(wx[i].z, wx[i].w);
        *(uint2*)&Bb[0][(rr + i * 16) * 72 + c4 * 4] = pw;
    }

    int p = 0;
    for (int kt = 0; kt < E_ / 64; ++kt) {
        __syncthreads();
        const bool more = (kt + 1) < E_ / 64;
        if (more) {
            const int kn = (kt + 1) * 64;
            #pragma unroll
            for (int i = 0; i < 4; ++i) {
                ax[i] = *(const float4*)&Xin[(size_t)(m0 + rr + i * 16) * E_ + kn + c4 * 4];
                wx[i] = *(const float4*)&W[(size_t)(n0 + rr + i * 16) * E_ + kn + c4 * 4];
            }
        }

        #pragma unroll
        for (int ks = 0; ks < 2; ++ks) {
            short8 b0 = *(const short8*)&Bb[p][(wc + l16) * 72 + quad * 8 + ks * 32];
            short8 b1 = *(const short8*)&Bb[p][(wc + 16 + l16) * 72 + quad * 8 + ks * 32];
            #pragma unroll
            for (int mi = 0; mi < 2; ++mi) {
                short8 a = *(const short8*)&Ab[p][(wr + mi * 16 + l16) * 72 + quad * 8 + ks * 32];
                acc[mi][0] = __builtin_amdgcn_mfma_f32_16x16x32_bf16(a, b0, acc[mi][0], 0, 0, 0);
                acc[mi][1] = __builtin_amdgcn_mfma_f32_16x16x32_bf16(a, b1, acc[mi][1], 0, 0, 0);
            }
        }

        if (more) {
            #pragma unroll
            for (int i = 0; i < 4; ++i) {
                uint2 pa; pa.x = pack2(ax[i].x, ax[i].y); pa.y = pack2(ax[i].z, ax[i].w);
                *(uint2*)&Ab[p ^ 1][(rr + i * 16) * 72 + c4 * 4] = pa;
                uint2 pw; pw.x = pack2(wx[i].x, wx[i].y); pw.y = pack2(wx[i].z, wx[i].w);
                *(uint2*)&Bb[p ^ 1][(rr + i * 16) * 72 + c4 * 4] = pw;
            }
        }
        p ^= 1;
    }

    #pragma unroll
    for (int ni = 0; ni < 2; ++ni) {
        const int n = n0 + wc + ni * 16 + l16;
        const float bw = bias[n];
        #pragma unroll
        for (int mi = 0; mi < 2; ++mi)
            #pragma unroll
            for (int r = 0; r < 4; ++r) {
                const int m = m0 + wr + mi * 16 + quad * 4 + r;
                Out[(size_t)m * E_ + n] = acc[mi][ni][r] + bw;
            }
    }
}

// ---------------------------------------------------------------------------
extern "C" void kernel_launch(void* const* d_in, const int* in_sizes, int n_in,
                              void* d_out, int out_size, void* d_ws, size_t ws_size,
                              hipStream_t stream)
{
    const float* q_in  = (const float*)d_in[0];
    const float* k_in  = (const float*)d_in[1];
    const float* v_in  = (const float*)d_in[2];
    const float* pb    = (const float*)d_in[3];
    const int*   mask  = (const int*)d_in[4];
    const float* wq    = (const float*)d_in[5];
    const float* bq    = (const float*)d_in[6];
    const float* wk    = (const float*)d_in[7];
    const float* bk    = (const float*)d_in[8];
    const float* wv    = (const float*)d_in[9];
    const float* bv    = (const float*)d_in[10];
    const float* fw    = (const float*)d_in[11];
    const float* fb    = (const float*)d_in[12];
    const float* coeff = (const float*)d_in[13];
    float* out = (float*)d_out;

    const size_t per = (size_t)B_ * H_ * S_ * D_;   // 3,145,728 elements
    float* Att = (float*)d_ws;                       // [B,S,E] fp32
    ush*   Qb  = (ush*)(Att + per);                  // bf16 [B,H,S,D]
    ush*   Kb  = Qb + per;
    ush*   Vtb = Kb + per;                           // bf16 [B,H,D,S]

    qkv_mfma_kernel<<<dim3(M_ / 64, E_ / 64, 3), 256, 0, stream>>>(
        q_in, k_in, v_in, wq, bq, wk, bk, wv, bv, Qb, Kb, Vtb);

    attn_kernel<<<dim3(S_ / 64, H_, B_), 256, 0, stream>>>(
        Qb, Kb, Vtb, pb, mask, coeff, Att);

    fc_mfma_kernel<<<dim3(M_ / 64, E_ / 64), 256, 0, stream>>>(Att, fw, fb, out);
}

// Round 16
// 227.399 us; speedup vs baseline: 1.2296x; 1.0017x over previous
//
#include <hip/hip_runtime.h>
#include <hip/hip_bf16.h>
#include <math.h>

#define B_ 2
#define S_ 2048
#define E_ 768
#define H_ 12
#define D_ 64
#define M_ (B_*S_)    // 4096 rows total
#define BH_ (B_*H_)   // 24

typedef unsigned short ush;
using short8 = __attribute__((ext_vector_type(8))) short;   // 8 bf16 (4 VGPRs)
using f32x4  = __attribute__((ext_vector_type(4))) float;   // MFMA C/D

__device__ __forceinline__ ush f2b(float x) {               // fp32 -> bf16 RNE
    union { float f; unsigned u; } v; v.f = x;
    unsigned r = v.u + 0x7fffu + ((v.u >> 16) & 1u);
    return (ush)(r >> 16);
}
// fp32 pair -> packed bf16: round-half-up + v_perm_b32 (3 VALU ops).
__device__ __forceinline__ unsigned pack2(float x, float y) {
    unsigned bx = __float_as_uint(x) + 0x8000u;
    unsigned by = __float_as_uint(y) + 0x8000u;
    return __builtin_amdgcn_perm(by, bx, 0x07060302u);  // [bx.hi16 | by.hi16<<16]
}

// ---------------------------------------------------------------------------
// Kernel 0: RoPE cos/sin table. R15 analysis: qkv epilogue ran 6.3M library
// sincosf (args up to 2048 rad) ~ 40% of qkv time. Table computes the SAME
// expf+sincosf values once (bit-identical). tab[s*32+i] = (cos, sin).
// grid 256 x 256.
// ---------------------------------------------------------------------------
__global__ __launch_bounds__(256) void rope_table_kernel(float2* __restrict__ tab)
{
    const int idx = blockIdx.x * 256 + threadIdx.x;   // 0..65535
    const int s = idx >> 5, i = idx & 31;
    const float ln1e4 = 9.210340371976184f;
    const float inv_freq = expf(-((float)(2 * i) / 64.f) * ln1e4);
    float sn, cs;
    sincosf((float)s * inv_freq, &sn, &cs);
    tab[idx] = make_float2(cs, sn);
}

// ---------------------------------------------------------------------------
// Kernel 1: QKV projection, single-bf16 MFMA GEMM, double-buffered staging
// (R13 structure). Epilogue RoPE now reads the precomputed table.
// grid (M/64, E/64=H, 3).
// ---------------------------------------------------------------------------
__global__ __launch_bounds__(256) void qkv_mfma_kernel(
    const float* __restrict__ q_in, const float* __restrict__ k_in, const float* __restrict__ v_in,
    const float* __restrict__ wq, const float* __restrict__ bq,
    const float* __restrict__ wk, const float* __restrict__ bk,
    const float* __restrict__ wv, const float* __restrict__ bv,
    const float2* __restrict__ rope,
    ush* __restrict__ Qb, ush* __restrict__ Kb, ush* __restrict__ Vtb)
{
    const int z = blockIdx.z;
    const float* __restrict__ X    = (z == 0) ? q_in : (z == 1) ? k_in : v_in;
    const float* __restrict__ W    = (z == 0) ? wq   : (z == 1) ? wk   : wv;
    const float* __restrict__ bias = (z == 0) ? bq   : (z == 1) ? bk   : bv;

    __shared__ ush Ab[2][64 * 72];
    __shared__ ush Bb[2][64 * 72];

    const int m0 = blockIdx.x * 64;
    const int n0 = blockIdx.y * 64;
    const int t  = threadIdx.x;
    const int wid  = t >> 6;
    const int lane = t & 63;
    const int quad = lane >> 4;
    const int l16  = lane & 15;
    const int wr = (wid >> 1) * 32;
    const int wc = (wid & 1) * 32;
    const int rr = t >> 4;
    const int c4 = t & 15;

    f32x4 acc[2][2];
    #pragma unroll
    for (int i = 0; i < 2; ++i)
        #pragma unroll
        for (int j = 0; j < 2; ++j) acc[i][j] = (f32x4){0.f, 0.f, 0.f, 0.f};

    float4 ax[4], wx[4];
    #pragma unroll
    for (int i = 0; i < 4; ++i) {
        ax[i] = *(const float4*)&X[(size_t)(m0 + rr + i * 16) * E_ + c4 * 4];
        wx[i] = *(const float4*)&W[(size_t)(n0 + rr + i * 16) * E_ + c4 * 4];
    }
    #pragma unroll
    for (int i = 0; i < 4; ++i) {
        uint2 pa; pa.x = pack2(ax[i].x, ax[i].y); pa.y = pack2(ax[i].z, ax[i].w);
        *(uint2*)&Ab[0][(rr + i * 16) * 72 + c4 * 4] = pa;
        uint2 pw; pw.x = pack2(wx[i].x, wx[i].y); pw.y = pack2(wx[i].z, wx[i].w);
        *(uint2*)&Bb[0][(rr + i * 16) * 72 + c4 * 4] = pw;
    }

    int p = 0;
    for (int kt = 0; kt < E_ / 64; ++kt) {
        __syncthreads();
        const bool more = (kt + 1) < E_ / 64;
        if (more) {
            const int kn = (kt + 1) * 64;
            #pragma unroll
            for (int i = 0; i < 4; ++i) {
                ax[i] = *(const float4*)&X[(size_t)(m0 + rr + i * 16) * E_ + kn + c4 * 4];
                wx[i] = *(const float4*)&W[(size_t)(n0 + rr + i * 16) * E_ + kn + c4 * 4];
            }
        }

        #pragma unroll
        for (int ks = 0; ks < 2; ++ks) {
            short8 b0 = *(const short8*)&Bb[p][(wc + l16) * 72 + quad * 8 + ks * 32];
            short8 b1 = *(const short8*)&Bb[p][(wc + 16 + l16) * 72 + quad * 8 + ks * 32];
            #pragma unroll
            for (int mi = 0; mi < 2; ++mi) {
                short8 a = *(const short8*)&Ab[p][(wr + mi * 16 + l16) * 72 + quad * 8 + ks * 32];
                acc[mi][0] = __builtin_amdgcn_mfma_f32_16x16x32_bf16(a, b0, acc[mi][0], 0, 0, 0);
                acc[mi][1] = __builtin_amdgcn_mfma_f32_16x16x32_bf16(a, b1, acc[mi][1], 0, 0, 0);
            }
        }

        if (more) {
            #pragma unroll
            for (int i = 0; i < 4; ++i) {
                uint2 pa; pa.x = pack2(ax[i].x, ax[i].y); pa.y = pack2(ax[i].z, ax[i].w);
                *(uint2*)&Ab[p ^ 1][(rr + i * 16) * 72 + c4 * 4] = pa;
                uint2 pw; pw.x = pack2(wx[i].x, wx[i].y); pw.y = pack2(wx[i].z, wx[i].w);
                *(uint2*)&Bb[p ^ 1][(rr + i * 16) * 72 + c4 * 4] = pw;
            }
        }
        p ^= 1;
    }

    // ---- epilogue ----  (whole block is one head: h = blockIdx.y)
    const int h = blockIdx.y;
    if (z < 2) {
        ush* __restrict__ Ob = (z == 0) ? Qb : Kb;
        #pragma unroll
        for (int ni = 0; ni < 2; ++ni) {
            const int d = wc + ni * 16 + l16;        // 0..63 within head
            const float bw = bias[n0 + d];
            const int pidx = d >> 1;                 // RoPE pair index
            const bool even = (d & 1) == 0;
            #pragma unroll
            for (int mi = 0; mi < 2; ++mi) {
                #pragma unroll
                for (int r = 0; r < 4; ++r) {
                    const int m = m0 + wr + mi * 16 + quad * 4 + r;
                    const int bb = m >> 11, s = m & (S_ - 1);
                    float v = acc[mi][ni][r] + bw;
                    float part = __shfl_xor(v, 1);          // pair value (d^1)
                    float2 tc = rope[s * 32 + pidx];
                    float rot = even ? (v * tc.x - part * tc.y) : (v * tc.x + part * tc.y);
                    ush pr = f2b(rot);
                    ush pp = (ush)__shfl_xor((int)pr, 1);   // partner's rotated
                    if (even) {
                        size_t o = (((size_t)bb * H_ + h) * S_ + s) * (size_t)D_ + d;
                        *(unsigned*)&Ob[o] = (unsigned)pr | ((unsigned)pp << 16);
                    }
                }
            }
        }
    } else {
        #pragma unroll
        for (int ni = 0; ni < 2; ++ni) {
            const int d = wc + ni * 16 + l16;
            const float bw = bias[n0 + d];
            #pragma unroll
            for (int mi = 0; mi < 2; ++mi) {
                const int m = m0 + wr + mi * 16 + quad * 4;  // r spans 4 consecutive s
                const int bb = m >> 11, sb = m & (S_ - 1);
                size_t o = (((size_t)bb * H_ + h) * D_ + d) * (size_t)S_ + sb;
                uint2 pk;
                pk.x = pack2(acc[mi][ni][0] + bw, acc[mi][ni][1] + bw);
                pk.y = pack2(acc[mi][ni][2] + bw, acc[mi][ni][3] + bw);
                *(uint2*)&Vtb[o] = pk;
            }
        }
    }
}

// ---------------------------------------------------------------------------
// Kernel 2: MFMA flash attention, fixed-max softmax, SPLIT-K over keys.
// Fixed-max partials are exactly additive: block (split) handles tps tiles,
// writes unnormalized O_part [split][bh][q][d] + l_part [split][bh][q].
// Ones-column B-frag is a constant (l16==0 ? 1 : 0) -> registers; Vt ones
// rows and their 2 ds_reads/iter removed. grid (S/64, H, B*NS), block 256.
// ---------------------------------------------------------------------------
__global__ __launch_bounds__(256) void attn_kernel(
    const ush* __restrict__ Qb, const ush* __restrict__ Kb, const ush* __restrict__ Vtb,
    const float* __restrict__ pb, const int* __restrict__ mask, const float* __restrict__ coeff,
    float* __restrict__ Opart, float* __restrict__ lpart, int NS, int tps)
{
    __shared__ ush  Ks[64 * 72];       // [key][d]
    __shared__ ush  Vt[64 * 72];       // [d][key]
    __shared__ ush  Ps[64 * 72];       // P rows [q][key] (wave-strip private)
    __shared__ float kb_s[64];         // per-key bias: (mask?0:-1e30) - ch*pb[k]

    const int q0    = blockIdx.x * 64;
    const int h     = blockIdx.y;
    const int b     = blockIdx.z / NS;
    const int split = blockIdx.z % NS;
    const int t  = threadIdx.x;
    const int wid = t >> 6;
    const int lane = t & 63;
    const int quad = lane >> 4;
    const int l16  = lane & 15;

    const int bh = b * H_ + h;
    const float ch = coeff[h];

    // constant ones-column B fragment: lane l16==0 holds 1.0 for all k
    short8 bOnes;
    {
        ush ov = (l16 == 0) ? (ush)0x3F80 : (ush)0;
        #pragma unroll
        for (int j = 0; j < 8; ++j) bOnes[j] = (short)ov;
    }

    const int qrow = q0 + wid * 16 + l16;
    short8 aQ[2];
    #pragma unroll
    for (int ks = 0; ks < 2; ++ks)
        aQ[ks] = *(const short8*)&Qb[((size_t)bh * S_ + qrow) * D_ + quad * 8 + ks * 32];

    float hp[4];
    #pragma unroll
    for (int r = 0; r < 4; ++r)
        hp[r] = ch * pb[b * S_ + q0 + wid * 16 + quad * 4 + r];

    f32x4 O[5];                        // O[4] = row-sum accumulator (ones-column)
    #pragma unroll
    for (int g = 0; g < 5; ++g) O[g] = (f32x4){0.f, 0.f, 0.f, 0.f};

    const int kt0 = split * tps;
    for (int kt = kt0; kt < kt0 + tps; ++kt) {
        const int k0 = kt * 64;
        __syncthreads();               // prior tile's frag reads done
        {
            const uint4* srcK = (const uint4*)(Kb + ((size_t)bh * S_ + k0) * D_);
            #pragma unroll
            for (int it = 0; it < 2; ++it) {
                int idx = t + it * 256;
                int row = idx >> 3, chk = idx & 7;
                *(uint4*)&Ks[row * 72 + chk * 8] = srcK[idx];
                const uint4* srcV = (const uint4*)(Vtb + ((size_t)bh * D_ + row) * S_ + k0);
                *(uint4*)&Vt[row * 72 + chk * 8] = srcV[chk];
            }
        }
        if (t < 64) {
            int gi = b * S_ + k0 + t;
            kb_s[t] = (mask[gi] ? 0.f : -1e30f) - ch * pb[gi];
        }
        __syncthreads();

        // ---- QK^T ----
        f32x4 Sc[4];
        #pragma unroll
        for (int cg = 0; cg < 4; ++cg) Sc[cg] = (f32x4){0.f, 0.f, 0.f, 0.f};
        #pragma unroll
        for (int ks = 0; ks < 2; ++ks) {
            #pragma unroll
            for (int cg = 0; cg < 4; ++cg) {
                short8 bK = *(const short8*)&Ks[(cg * 16 + l16) * 72 + quad * 8 + ks * 32];
                Sc[cg] = __builtin_amdgcn_mfma_f32_16x16x32_bf16(aQ[ks], bK, Sc[cg], 0, 0, 0);
            }
        }

        // ---- fixed-max softmax numerators -> Ps (bf16 truncation) ----
        float kbv[4];
        #pragma unroll
        for (int cg = 0; cg < 4; ++cg) kbv[cg] = kb_s[cg * 16 + l16];
        #pragma unroll
        for (int cg = 0; cg < 4; ++cg)
            #pragma unroll
            for (int r = 0; r < 4; ++r) {
                float s = fmaf(Sc[cg][r], 0.125f, hp[r] + kbv[cg]);
                float pv = __expf(s);  // masked: s ~ -1e30 -> p = 0 exactly
                Ps[(wid * 16 + quad * 4 + r) * 72 + cg * 16 + l16] =
                    (ush)(__float_as_uint(pv) >> 16);
            }
        // no barrier: Ps strip is wave-private (intra-wave LDS RAW, lgkmcnt)

        // ---- PV (+ ones-column row-sum into O[4]) ----
        #pragma unroll
        for (int ks = 0; ks < 2; ++ks) {
            short8 aP = *(const short8*)&Ps[(wid * 16 + l16) * 72 + quad * 8 + ks * 32];
            #pragma unroll
            for (int g = 0; g < 4; ++g) {
                short8 bV = *(const short8*)&Vt[(g * 16 + l16) * 72 + quad * 8 + ks * 32];
                O[g] = __builtin_amdgcn_mfma_f32_16x16x32_bf16(aP, bV, O[g], 0, 0, 0);
            }
            O[4] = __builtin_amdgcn_mfma_f32_16x16x32_bf16(aP, bOnes, O[4], 0, 0, 0);
        }
    }

    // epilogue: write unnormalized partials
    float* __restrict__ Op = Opart + ((size_t)(split * BH_ + bh) * S_ + q0) * D_;
    float* __restrict__ Lp = lpart + (size_t)(split * BH_ + bh) * S_ + q0;
    #pragma unroll
    for (int r = 0; r < 4; ++r) {
        const int ql = wid * 16 + quad * 4 + r;   // local q row
        #pragma unroll
        for (int g = 0; g < 4; ++g)
            Op[(size_t)ql * D_ + g * 16 + l16] = O[g][r];
        if (l16 == 0) Lp[ql] = O[4][r];
    }
}

// ---------------------------------------------------------------------------
// Kernel 2b: sum splits, normalize, emit Att as bf16 (same pack2 fc used at
// staging -> numerically identical fc input). grid 3072 x 256.
// ---------------------------------------------------------------------------
__global__ __launch_bounds__(256) void reduce_kernel(
    const float* __restrict__ Opart, const float* __restrict__ lpart,
    ush* __restrict__ Attb, int NS)
{
    const int g4 = blockIdx.x * 256 + threadIdx.x;   // float4 index, 786432 total
    const int d4  = g4 & 15;
    const int qbh = g4 >> 4;                          // bh*2048 + q
    const int q  = qbh & (S_ - 1);
    const int bh = qbh >> 11;

    float4 o = ((const float4*)Opart)[g4];
    float l = lpart[qbh];
    if (NS == 2) {
        const float4 o2 = ((const float4*)(Opart + (size_t)BH_ * S_ * D_))[g4];
        o.x += o2.x; o.y += o2.y; o.z += o2.z; o.w += o2.w;
        l += lpart[(size_t)BH_ * S_ + qbh];
    }
    const float rl = 1.f / l;
    const int b = bh / H_, h = bh % H_;
    const size_t off = ((size_t)(b * S_ + q)) * E_ + h * 64 + d4 * 4;
    uint2 pk;
    pk.x = pack2(o.x * rl, o.y * rl);
    pk.y = pack2(o.z * rl, o.w * rl);
    *(uint2*)&Attb[off] = pk;
}

// ---------------------------------------------------------------------------
// Kernel 3: output projection. A operand (Att) is now bf16 -> staging is a
// pure copy (no conversion VALU). B (fc_w fp32) unchanged. Double-buffered.
// grid (M/64, E/64).
// ---------------------------------------------------------------------------
__global__ __launch_bounds__(256) void fc_mfma_kernel(
    const ush* __restrict__ Attb, const float* __restrict__ W,
    const float* __restrict__ bias, float* __restrict__ Out)
{
    __shared__ ush Ab[2][64 * 72];
    __shared__ ush Bb[2][64 * 72];

    const int m0 = blockIdx.x * 64;
    const int n0 = blockIdx.y * 64;
    const int t  = threadIdx.x;
    const int wid  = t >> 6;
    const int lane = t & 63;
    const int quad = lane >> 4;
    const int l16  = lane & 15;
    const int wr = (wid >> 1) * 32;
    const int wc = (wid & 1) * 32;
    const int rr = t >> 4;             // fp32 B staging row base
    const int c4 = t & 15;
    const int ra = t >> 3;             // bf16 A staging: row 0..31 base
    const int ca = t & 7;              // 16B chunk

    f32x4 acc[2][2];
    #pragma unroll
    for (int i = 0; i < 2; ++i)
        #pragma unroll
        for (int j = 0; j < 2; ++j) acc[i][j] = (f32x4){0.f, 0.f, 0.f, 0.f};

    uint4  ax[2];
    float4 wx[4];
    #pragma unroll
    for (int i = 0; i < 2; ++i)
        ax[i] = *(const uint4*)&Attb[(size_t)(m0 + ra + i * 32) * E_ + ca * 8];
    #pragma unroll
    for (int i = 0; i < 4; ++i)
        wx[i] = *(const float4*)&W[(size_t)(n0 + rr + i * 16) * E_ + c4 * 4];
    #pragma unroll
    for (int i = 0; i < 2; ++i)
        *(uint4*)&Ab[0][(ra + i * 32) * 72 + ca * 8] = ax[i];
    #pragma unroll
    for (int i = 0; i < 4; ++i) {
        uint2 pw; pw.x = pack2(wx[i].x, wx[i].y); pw.y = pack2(wx[i].z, wx[i].w);
        *(uint2*)&Bb[0][(rr + i * 16) * 72 + c4 * 4] = pw;
    }

    int p = 0;
    for (int kt = 0; kt < E_ / 64; ++kt) {
        __syncthreads();
        const bool more = (kt + 1) < E_ / 64;
        if (more) {
            const int kn = (kt + 1) * 64;
            #pragma unroll
            for (int i = 0; i < 2; ++i)
                ax[i] = *(const uint4*)&Attb[(size_t)(m0 + ra + i * 32) * E_ + kn + ca * 8];
            #pragma unroll
            for (int i = 0; i < 4; ++i)
                wx[i] = *(const float4*)&W[(size_t)(n0 + rr + i * 16) * E_ + kn + c4 * 4];
        }

        #pragma unroll
        for (int ks = 0; ks < 2; ++ks) {
            short8 b0 = *(const short8*)&Bb[p][(wc + l16) * 72 + quad * 8 + ks * 32];
            short8 b1 = *(const short8*)&Bb[p][(wc + 16 + l16) * 72 + quad * 8 + ks * 32];
            #pragma unroll
            for (int mi = 0; mi < 2; ++mi) {
                short8 a = *(const short8*)&Ab[p][(wr + mi * 16 + l16) * 72 + quad * 8 + ks * 32];
                acc[mi][0] = __builtin_amdgcn_mfma_f32_16x16x32_bf16(a, b0, acc[mi][0], 0, 0, 0);
                acc[mi][1] = __builtin_amdgcn_mfma_f32_16x16x32_bf16(a, b1, acc[mi][1], 0, 0, 0);
            }
        }

        if (more) {
            #pragma unroll
            for (int i = 0; i < 2; ++i)
                *(uint4*)&Ab[p ^ 1][(ra + i * 32) * 72 + ca * 8] = ax[i];
            #pragma unroll
            for (int i = 0; i < 4; ++i) {
                uint2 pw; pw.x = pack2(wx[i].x, wx[i].y); pw.y = pack2(wx[i].z, wx[i].w);
                *(uint2*)&Bb[p ^ 1][(rr + i * 16) * 72 + c4 * 4] = pw;
            }
        }
        p ^= 1;
    }

    #pragma unroll
    for (int ni = 0; ni < 2; ++ni) {
        const int n = n0 + wc + ni * 16 + l16;
        const float bw = bias[n];
        #pragma unroll
        for (int mi = 0; mi < 2; ++mi)
            #pragma unroll
            for (int r = 0; r < 4; ++r) {
                const int m = m0 + wr + mi * 16 + quad * 4 + r;
                Out[(size_t)m * E_ + n] = acc[mi][ni][r] + bw;
            }
    }
}

// ---------------------------------------------------------------------------
extern "C" void kernel_launch(void* const* d_in, const int* in_sizes, int n_in,
                              void* d_out, int out_size, void* d_ws, size_t ws_size,
                              hipStream_t stream)
{
    const float* q_in  = (const float*)d_in[0];
    const float* k_in  = (const float*)d_in[1];
    const float* v_in  = (const float*)d_in[2];
    const float* pb    = (const float*)d_in[3];
    const int*   mask  = (const int*)d_in[4];
    const float* wq    = (const float*)d_in[5];
    const float* bq    = (const float*)d_in[6];
    const float* wk    = (const float*)d_in[7];
    const float* bk    = (const float*)d_in[8];
    const float* wv    = (const float*)d_in[9];
    const float* bv    = (const float*)d_in[10];
    const float* fw    = (const float*)d_in[11];
    const float* fb    = (const float*)d_in[12];
    const float* coeff = (const float*)d_in[13];
    float* out = (float*)d_out;

    const size_t per = (size_t)B_ * H_ * S_ * D_;   // 3,145,728 elements
    ush*    Qb   = (ush*)d_ws;                      // bf16 [B,H,S,D]
    ush*    Kb   = Qb + per;
    ush*    Vtb  = Kb + per;                        // bf16 [B,H,D,S]
    ush*    Attb = Vtb + per;                       // bf16 [B,S,E]
    float2* rope = (float2*)(Attb + per);           // 65536 float2
    float*  Opart = (float*)(rope + 65536);
    const size_t base = 4 * per * sizeof(ush) + 65536 * sizeof(float2);
    const size_t lsz  = (size_t)BH_ * S_;           // l elements per split
    const size_t need2 = base + 2 * per * sizeof(float) + 2 * lsz * sizeof(float);
    const int NS  = (ws_size >= need2) ? 2 : 1;
    const int tps = 32 / NS;                        // key tiles per split
    float* lpart = Opart + (size_t)NS * per;

    rope_table_kernel<<<256, 256, 0, stream>>>(rope);

    qkv_mfma_kernel<<<dim3(M_ / 64, E_ / 64, 3), 256, 0, stream>>>(
        q_in, k_in, v_in, wq, bq, wk, bk, wv, bv, rope, Qb, Kb, Vtb);

    attn_kernel<<<dim3(S_ / 64, H_, B_ * NS), 256, 0, stream>>>(
        Qb, Kb, Vtb, pb, mask, coeff, Opart, lpart, NS, tps);

    reduce_kernel<<<3072, 256, 0, stream>>>(Opart, lpart, Attb, NS);

    fc_mfma_kernel<<<dim3(M_ / 64, E_ / 64), 256, 0, stream>>>(Attb, fw, fb, out);
}